// Round 1
// baseline (127.878 us; speedup 1.0000x reference)
//
#include <hip/hip_runtime.h>

#define DELTA_VAR  0.5f
#define DELTA_DIST 1.5f
#define ALPHA 1.0f
#define BETA  1.0f
#define GAMMA 0.001f

constexpr int N = 2;
constexpr int E = 16;
constexpr int C = 16;
constexpr int V = 64 * 128 * 128;   // 1048576 voxels per batch
constexpr int NV4 = V / 4;          // float4 / int4 granularity

// workspace layout (floats)
constexpr int OFF_COUNTS = 0;       // N*C = 32
constexpr int OFF_SUMS   = 32;      // N*C*E = 512, layout (n*C+c)*E+e
constexpr int OFF_MEANS  = 544;     // 512
constexpr int OFF_HINGED = 1056;    // 32
constexpr int OFF_DIST   = 1088;    // 2
constexpr int OFF_REG    = 1090;    // 2
constexpr int WS_FLOATS  = 1092;

__global__ void zero_ws(float* __restrict__ ws) {
    for (int i = threadIdx.x; i < WS_FLOATS; i += blockDim.x) ws[i] = 0.0f;
}

// Pass 1: per-cluster sums of embeddings (and counts, in the e==0 planes).
// grid = (64, E, N), block = 256. Each block handles one (n, e) plane chunk.
__global__ __launch_bounds__(256) void pass1_sums(
    const float* __restrict__ x, const int* __restrict__ t, float* __restrict__ ws) {
    const int e = blockIdx.y;
    const int n = blockIdx.z;
    const float4* __restrict__ xp =
        reinterpret_cast<const float4*>(x + ((size_t)n * E + e) * (size_t)V);
    const int4* __restrict__ tp =
        reinterpret_cast<const int4*>(t + (size_t)n * V);

    float acc[C];
    float cnt[C];
#pragma unroll
    for (int c = 0; c < C; ++c) { acc[c] = 0.0f; cnt[c] = 0.0f; }

    const bool do_count = (e == 0);
    const int stride = gridDim.x * blockDim.x;
    for (int i = blockIdx.x * blockDim.x + threadIdx.x; i < NV4; i += stride) {
        const float4 xv = xp[i];
        const int4   tv = tp[i];
#pragma unroll
        for (int c = 0; c < C; ++c) {
            float a = acc[c];
            a += (tv.x == c) ? xv.x : 0.0f;
            a += (tv.y == c) ? xv.y : 0.0f;
            a += (tv.z == c) ? xv.z : 0.0f;
            a += (tv.w == c) ? xv.w : 0.0f;
            acc[c] = a;
        }
        if (do_count) {
#pragma unroll
            for (int c = 0; c < C; ++c) {
                float a = cnt[c];
                a += (tv.x == c) ? 1.0f : 0.0f;
                a += (tv.y == c) ? 1.0f : 0.0f;
                a += (tv.z == c) ? 1.0f : 0.0f;
                a += (tv.w == c) ? 1.0f : 0.0f;
                cnt[c] = a;
            }
        }
    }

    __shared__ float s_acc[C];
    __shared__ float s_cnt[C];
    if (threadIdx.x < C) { s_acc[threadIdx.x] = 0.0f; s_cnt[threadIdx.x] = 0.0f; }
    __syncthreads();
    const int lane = threadIdx.x & 63;
#pragma unroll
    for (int c = 0; c < C; ++c) {
        float v = acc[c];
#pragma unroll
        for (int off = 32; off > 0; off >>= 1) v += __shfl_down(v, off);
        if (lane == 0) atomicAdd(&s_acc[c], v);
        if (do_count) {
            float w = cnt[c];
#pragma unroll
            for (int off = 32; off > 0; off >>= 1) w += __shfl_down(w, off);
            if (lane == 0) atomicAdd(&s_cnt[c], w);
        }
    }
    __syncthreads();
    if (threadIdx.x < C) {
        atomicAdd(&ws[OFF_SUMS + ((size_t)n * C + threadIdx.x) * E + e], s_acc[threadIdx.x]);
        if (do_count)
            atomicAdd(&ws[OFF_COUNTS + n * C + threadIdx.x], s_cnt[threadIdx.x]);
    }
}

// Means + distance term + regularizer. 1 block, 512 threads (= N*C*E = N*C*C).
__global__ void finalize_means(float* __restrict__ ws) {
    const int tid = threadIdx.x;  // 0..511
    __shared__ float s_m[N * C * E];
    const float mval = ws[OFF_SUMS + tid] / ws[OFF_COUNTS + tid / E];
    ws[OFF_MEANS + tid] = mval;
    s_m[tid] = mval;
    __shared__ float s_dist[N], s_reg[N];
    if (tid < N) { s_dist[tid] = 0.0f; s_reg[tid] = 0.0f; }
    __syncthreads();

    const int n = tid >> 8;
    const int i = (tid >> 4) & 15;
    const int j = tid & 15;
    const float* mi = &s_m[(n * C + i) * E];
    const float* mj = &s_m[(n * C + j) * E];
    float d2 = 0.0f;
#pragma unroll
    for (int e2 = 0; e2 < E; ++e2) { const float df = mi[e2] - mj[e2]; d2 = fmaf(df, df, d2); }
    float contrib = 0.0f;
    if (i != j) {
        const float hd = 2.0f * DELTA_DIST - sqrtf(d2);
        if (hd > 0.0f) contrib = hd * hd;
    }
    atomicAdd(&s_dist[n], contrib);
    if (i == j) {
        float s = 0.0f;
#pragma unroll
        for (int e2 = 0; e2 < E; ++e2) s = fmaf(mi[e2], mi[e2], s);
        atomicAdd(&s_reg[n], sqrtf(s));
    }
    __syncthreads();
    if (tid < N) {
        ws[OFF_DIST + tid] = s_dist[tid] / (float)(C * (C - 1));
        ws[OFF_REG + tid]  = s_reg[tid] / (float)C;
    }
}

// Pass 2: hinged squared distance of each voxel to its own cluster mean,
// accumulated per cluster. grid = (1024, 1, N), block = 256.
__global__ __launch_bounds__(256) void pass2_var(
    const float* __restrict__ x, const int* __restrict__ t, float* __restrict__ ws) {
    const int n = blockIdx.z;
    __shared__ float s_mt[E][C];  // transposed: conflict-free broadcast reads
    if (threadIdx.x < C * E) {
        const int c = threadIdx.x / E;
        const int e = threadIdx.x % E;
        s_mt[e][c] = ws[OFF_MEANS + (size_t)(n * C + c) * E + e];
    }
    __syncthreads();

    const float* __restrict__ xb = x + (size_t)n * E * V;
    const int4* __restrict__ tp = reinterpret_cast<const int4*>(t + (size_t)n * V);

    float acc[C];
#pragma unroll
    for (int c = 0; c < C; ++c) acc[c] = 0.0f;

    const int stride = gridDim.x * blockDim.x;
    for (int i = blockIdx.x * blockDim.x + threadIdx.x; i < NV4; i += stride) {
        const int4 tv = tp[i];
        float d0 = 0.0f, d1 = 0.0f, d2 = 0.0f, d3 = 0.0f;
#pragma unroll
        for (int e = 0; e < E; ++e) {
            const float4 xv =
                *reinterpret_cast<const float4*>(xb + (size_t)e * V + (size_t)i * 4);
            float u;
            u = xv.x - s_mt[e][tv.x]; d0 = fmaf(u, u, d0);
            u = xv.y - s_mt[e][tv.y]; d1 = fmaf(u, u, d1);
            u = xv.z - s_mt[e][tv.z]; d2 = fmaf(u, u, d2);
            u = xv.w - s_mt[e][tv.w]; d3 = fmaf(u, u, d3);
        }
        float h0 = sqrtf(d0) - DELTA_VAR; h0 = (h0 > 0.0f) ? h0 * h0 : 0.0f;
        float h1 = sqrtf(d1) - DELTA_VAR; h1 = (h1 > 0.0f) ? h1 * h1 : 0.0f;
        float h2 = sqrtf(d2) - DELTA_VAR; h2 = (h2 > 0.0f) ? h2 * h2 : 0.0f;
        float h3 = sqrtf(d3) - DELTA_VAR; h3 = (h3 > 0.0f) ? h3 * h3 : 0.0f;
#pragma unroll
        for (int c = 0; c < C; ++c) {
            float a = acc[c];
            a += (tv.x == c) ? h0 : 0.0f;
            a += (tv.y == c) ? h1 : 0.0f;
            a += (tv.z == c) ? h2 : 0.0f;
            a += (tv.w == c) ? h3 : 0.0f;
            acc[c] = a;
        }
    }

    __shared__ float s_acc[C];
    if (threadIdx.x < C) s_acc[threadIdx.x] = 0.0f;
    __syncthreads();
    const int lane = threadIdx.x & 63;
#pragma unroll
    for (int c = 0; c < C; ++c) {
        float v = acc[c];
#pragma unroll
        for (int off = 32; off > 0; off >>= 1) v += __shfl_down(v, off);
        if (lane == 0) atomicAdd(&s_acc[c], v);
    }
    __syncthreads();
    if (threadIdx.x < C)
        atomicAdd(&ws[OFF_HINGED + n * C + threadIdx.x], s_acc[threadIdx.x]);
}

// Combine: variance term + dist + reg -> scalar loss. 1 block, 64 threads.
__global__ void final_loss(const float* __restrict__ ws, float* __restrict__ out) {
    const int tid = threadIdx.x;
    float v = 0.0f;
    if (tid < N * C) v = ws[OFF_HINGED + tid] / ws[OFF_COUNTS + tid];
#pragma unroll
    for (int off = 8; off > 0; off >>= 1) v += __shfl_down(v, off);
    const float s0 = __shfl(v, 0);
    const float s1 = __shfl(v, 16);
    if (tid == 0) {
        const float loss0 = ALPHA * (s0 / (float)C) + BETA * ws[OFF_DIST + 0] + GAMMA * ws[OFF_REG + 0];
        const float loss1 = ALPHA * (s1 / (float)C) + BETA * ws[OFF_DIST + 1] + GAMMA * ws[OFF_REG + 1];
        out[0] = 0.5f * (loss0 + loss1);
    }
}

extern "C" void kernel_launch(void* const* d_in, const int* in_sizes, int n_in,
                              void* d_out, int out_size, void* d_ws, size_t ws_size,
                              hipStream_t stream) {
    const float* x = (const float*)d_in[0];
    const int*   t = (const int*)d_in[1];
    float* ws  = (float*)d_ws;
    float* out = (float*)d_out;

    hipLaunchKernelGGL(zero_ws, dim3(1), dim3(256), 0, stream, ws);
    hipLaunchKernelGGL(pass1_sums, dim3(64, E, N), dim3(256), 0, stream, x, t, ws);
    hipLaunchKernelGGL(finalize_means, dim3(1), dim3(512), 0, stream, ws);
    hipLaunchKernelGGL(pass2_var, dim3(1024, 1, N), dim3(256), 0, stream, x, t, ws);
    hipLaunchKernelGGL(final_loss, dim3(1), dim3(64), 0, stream, ws, out);
}

// Round 2
// 86.112 us; speedup vs baseline: 1.4850x; 1.4850x over previous
//
#include <hip/hip_runtime.h>

#define DELTA_VAR  0.5f
#define DELTA_DIST 1.5f
#define ALPHA 1.0f
#define BETA  1.0f
#define GAMMA 0.001f

constexpr int N = 2;
constexpr int E = 16;
constexpr int C = 16;
constexpr int V = 64 * 128 * 128;   // 1048576 voxels per batch
constexpr int NV4 = V / 4;          // float4 / int4 granularity

// workspace layout (floats)
constexpr int OFF_COUNTS = 0;       // N*C = 32
constexpr int OFF_SUMS   = 32;      // N*C*E = 512, layout (n*C+c)*E+e
constexpr int OFF_MEANS  = 544;     // 512
constexpr int OFF_HINGED = 1056;    // 32
constexpr int OFF_DIST   = 1088;    // 2
constexpr int OFF_REG    = 1090;    // 2
constexpr int WS_FLOATS  = 1092;

typedef __attribute__((ext_vector_type(8))) short bf16x8;
typedef __attribute__((ext_vector_type(4))) float f32x4;

__device__ inline short f2bf(float f) {
    // round-to-nearest-even fp32 -> bf16 (inputs are finite normals)
    unsigned u = __builtin_bit_cast(unsigned, f);
    unsigned r = u + 0x7FFFu + ((u >> 16) & 1u);
    return (short)(r >> 16);
}

__global__ void zero_ws(float* __restrict__ ws) {
    for (int i = threadIdx.x; i < WS_FLOATS; i += blockDim.x) ws[i] = 0.0f;
}

// Pass 1 (MFMA): sums[c][e] = onehot[C][V] x X^T[V][E] via 16x16x32 bf16 MFMA.
// One MFMA consumes 32 voxels entirely (all 16 clusters x all 16 embeddings).
// A (onehot) and B (x) are both placed with the SAME (lane>>4, j) -> k slot
// mapping, so the result is invariant to the hardware's internal k order.
// grid = (512, N), block = 256 (4 waves). 2048 waves/n, 16 chunks each.
__global__ __launch_bounds__(256) void pass1_mfma(
    const float* __restrict__ x, const int* __restrict__ t, float* __restrict__ ws) {
    const int n    = blockIdx.y;
    const int lane = threadIdx.x & 63;
    const int wid  = threadIdx.x >> 6;
    const int wave = blockIdx.x * 4 + wid;        // 0..2047
    const int col  = lane & 15;                    // A row (=cluster) & B col (=e)
    const int kc   = lane >> 4;                    // 0..3 k-chunk within K=32

    const float* __restrict__ xn = x + (size_t)n * E * V;
    const int*   __restrict__ tn = t + (size_t)n * V;

    f32x4 acc = {0.f, 0.f, 0.f, 0.f};
    int cnt = 0;

    const int nwaves = gridDim.x * 4;              // 2048
    const int stride = nwaves * 32;                // voxels per sweep (65536)

#pragma unroll 2
    for (int vb = wave * 32; vb < V; vb += stride) {
        const int k0 = vb + kc * 8;
        const int4 t0 = *reinterpret_cast<const int4*>(tn + k0);
        const int4 t1 = *reinterpret_cast<const int4*>(tn + k0 + 4);
        const float* xp = xn + (size_t)col * V + k0;
        const float4 x0 = *reinterpret_cast<const float4*>(xp);
        const float4 x1 = *reinterpret_cast<const float4*>(xp + 4);

        bf16x8 bfrag;
        bfrag[0] = f2bf(x0.x); bfrag[1] = f2bf(x0.y);
        bfrag[2] = f2bf(x0.z); bfrag[3] = f2bf(x0.w);
        bfrag[4] = f2bf(x1.x); bfrag[5] = f2bf(x1.y);
        bfrag[6] = f2bf(x1.z); bfrag[7] = f2bf(x1.w);

        const short ONE = (short)0x3F80;           // bf16 1.0
        bf16x8 afrag;
        afrag[0] = (t0.x == col) ? ONE : (short)0; cnt += (t0.x == col);
        afrag[1] = (t0.y == col) ? ONE : (short)0; cnt += (t0.y == col);
        afrag[2] = (t0.z == col) ? ONE : (short)0; cnt += (t0.z == col);
        afrag[3] = (t0.w == col) ? ONE : (short)0; cnt += (t0.w == col);
        afrag[4] = (t1.x == col) ? ONE : (short)0; cnt += (t1.x == col);
        afrag[5] = (t1.y == col) ? ONE : (short)0; cnt += (t1.y == col);
        afrag[6] = (t1.z == col) ? ONE : (short)0; cnt += (t1.z == col);
        afrag[7] = (t1.w == col) ? ONE : (short)0; cnt += (t1.w == col);

        acc = __builtin_amdgcn_mfma_f32_16x16x32_bf16(afrag, bfrag, acc, 0, 0, 0);
    }

    // counts: lane holds matches for cluster col within its kc chunk;
    // fold the 4 kc groups down so lanes 0..15 hold per-cluster totals.
    cnt += __shfl_down(cnt, 32);
    cnt += __shfl_down(cnt, 16);

    // block-level reduction in LDS, then one global atomic per (block, c, e)
    __shared__ float s_sums[C * E];
    __shared__ float s_cnt[C];
    if (threadIdx.x < C * E) s_sums[threadIdx.x] = 0.0f;
    if (threadIdx.x < C)     s_cnt[threadIdx.x] = 0.0f;
    __syncthreads();
#pragma unroll
    for (int r = 0; r < 4; ++r) {
        const int c = kc * 4 + r;                  // D row mapping (m89-verified)
        atomicAdd(&s_sums[c * E + col], acc[r]);
    }
    if (lane < 16) atomicAdd(&s_cnt[lane], (float)cnt);
    __syncthreads();
    if (threadIdx.x < C * E)
        atomicAdd(&ws[OFF_SUMS + n * (C * E) + threadIdx.x], s_sums[threadIdx.x]);
    if (threadIdx.x < C)
        atomicAdd(&ws[OFF_COUNTS + n * C + threadIdx.x], s_cnt[threadIdx.x]);
}

// Means + distance term + regularizer. 1 block, 512 threads (= N*C*E = N*C*C).
__global__ void finalize_means(float* __restrict__ ws) {
    const int tid = threadIdx.x;  // 0..511
    __shared__ float s_m[N * C * E];
    const float mval = ws[OFF_SUMS + tid] / ws[OFF_COUNTS + tid / E];
    ws[OFF_MEANS + tid] = mval;
    s_m[tid] = mval;
    __shared__ float s_dist[N], s_reg[N];
    if (tid < N) { s_dist[tid] = 0.0f; s_reg[tid] = 0.0f; }
    __syncthreads();

    const int n = tid >> 8;
    const int i = (tid >> 4) & 15;
    const int j = tid & 15;
    const float* mi = &s_m[(n * C + i) * E];
    const float* mj = &s_m[(n * C + j) * E];
    float d2 = 0.0f;
#pragma unroll
    for (int e2 = 0; e2 < E; ++e2) { const float df = mi[e2] - mj[e2]; d2 = fmaf(df, df, d2); }
    float contrib = 0.0f;
    if (i != j) {
        const float hd = 2.0f * DELTA_DIST - sqrtf(d2);
        if (hd > 0.0f) contrib = hd * hd;
    }
    atomicAdd(&s_dist[n], contrib);
    if (i == j) {
        float s = 0.0f;
#pragma unroll
        for (int e2 = 0; e2 < E; ++e2) s = fmaf(mi[e2], mi[e2], s);
        atomicAdd(&s_reg[n], sqrtf(s));
    }
    __syncthreads();
    if (tid < N) {
        ws[OFF_DIST + tid] = s_dist[tid] / (float)(C * (C - 1));
        ws[OFF_REG + tid]  = s_reg[tid] / (float)C;
    }
}

// Pass 2: hinged squared distance of each voxel to its own cluster mean,
// accumulated per cluster. grid = (1024, 1, N), block = 256.
__global__ __launch_bounds__(256) void pass2_var(
    const float* __restrict__ x, const int* __restrict__ t, float* __restrict__ ws) {
    const int n = blockIdx.z;
    __shared__ float s_mt[E][C];  // transposed: conflict-free broadcast reads
    if (threadIdx.x < C * E) {
        const int c = threadIdx.x / E;
        const int e = threadIdx.x % E;
        s_mt[e][c] = ws[OFF_MEANS + (size_t)(n * C + c) * E + e];
    }
    __syncthreads();

    const float* __restrict__ xb = x + (size_t)n * E * V;
    const int4* __restrict__ tp = reinterpret_cast<const int4*>(t + (size_t)n * V);

    float acc[C];
#pragma unroll
    for (int c = 0; c < C; ++c) acc[c] = 0.0f;

    const int stride = gridDim.x * blockDim.x;
    for (int i = blockIdx.x * blockDim.x + threadIdx.x; i < NV4; i += stride) {
        const int4 tv = tp[i];
        float d0 = 0.0f, d1 = 0.0f, d2 = 0.0f, d3 = 0.0f;
#pragma unroll
        for (int e = 0; e < E; ++e) {
            const float4 xv =
                *reinterpret_cast<const float4*>(xb + (size_t)e * V + (size_t)i * 4);
            float u;
            u = xv.x - s_mt[e][tv.x]; d0 = fmaf(u, u, d0);
            u = xv.y - s_mt[e][tv.y]; d1 = fmaf(u, u, d1);
            u = xv.z - s_mt[e][tv.z]; d2 = fmaf(u, u, d2);
            u = xv.w - s_mt[e][tv.w]; d3 = fmaf(u, u, d3);
        }
        float h0 = sqrtf(d0) - DELTA_VAR; h0 = (h0 > 0.0f) ? h0 * h0 : 0.0f;
        float h1 = sqrtf(d1) - DELTA_VAR; h1 = (h1 > 0.0f) ? h1 * h1 : 0.0f;
        float h2 = sqrtf(d2) - DELTA_VAR; h2 = (h2 > 0.0f) ? h2 * h2 : 0.0f;
        float h3 = sqrtf(d3) - DELTA_VAR; h3 = (h3 > 0.0f) ? h3 * h3 : 0.0f;
#pragma unroll
        for (int c = 0; c < C; ++c) {
            float a = acc[c];
            a += (tv.x == c) ? h0 : 0.0f;
            a += (tv.y == c) ? h1 : 0.0f;
            a += (tv.z == c) ? h2 : 0.0f;
            a += (tv.w == c) ? h3 : 0.0f;
            acc[c] = a;
        }
    }

    __shared__ float s_acc[C];
    if (threadIdx.x < C) s_acc[threadIdx.x] = 0.0f;
    __syncthreads();
    const int lane = threadIdx.x & 63;
#pragma unroll
    for (int c = 0; c < C; ++c) {
        float v = acc[c];
#pragma unroll
        for (int off = 32; off > 0; off >>= 1) v += __shfl_down(v, off);
        if (lane == 0) atomicAdd(&s_acc[c], v);
    }
    __syncthreads();
    if (threadIdx.x < C)
        atomicAdd(&ws[OFF_HINGED + n * C + threadIdx.x], s_acc[threadIdx.x]);
}

// Combine: variance term + dist + reg -> scalar loss. 1 block, 64 threads.
__global__ void final_loss(const float* __restrict__ ws, float* __restrict__ out) {
    const int tid = threadIdx.x;
    float v = 0.0f;
    if (tid < N * C) v = ws[OFF_HINGED + tid] / ws[OFF_COUNTS + tid];
#pragma unroll
    for (int off = 8; off > 0; off >>= 1) v += __shfl_down(v, off);
    const float s0 = __shfl(v, 0);
    const float s1 = __shfl(v, 16);
    if (tid == 0) {
        const float loss0 = ALPHA * (s0 / (float)C) + BETA * ws[OFF_DIST + 0] + GAMMA * ws[OFF_REG + 0];
        const float loss1 = ALPHA * (s1 / (float)C) + BETA * ws[OFF_DIST + 1] + GAMMA * ws[OFF_REG + 1];
        out[0] = 0.5f * (loss0 + loss1);
    }
}

extern "C" void kernel_launch(void* const* d_in, const int* in_sizes, int n_in,
                              void* d_out, int out_size, void* d_ws, size_t ws_size,
                              hipStream_t stream) {
    const float* x = (const float*)d_in[0];
    const int*   t = (const int*)d_in[1];
    float* ws  = (float*)d_ws;
    float* out = (float*)d_out;

    hipLaunchKernelGGL(zero_ws, dim3(1), dim3(256), 0, stream, ws);
    hipLaunchKernelGGL(pass1_mfma, dim3(512, N), dim3(256), 0, stream, x, t, ws);
    hipLaunchKernelGGL(finalize_means, dim3(1), dim3(512), 0, stream, ws);
    hipLaunchKernelGGL(pass2_var, dim3(1024, 1, N), dim3(256), 0, stream, x, t, ws);
    hipLaunchKernelGGL(final_loss, dim3(1), dim3(64), 0, stream, ws, out);
}